// Round 1
// baseline (178.786 us; speedup 1.0000x reference)
//
#include <hip/hip_runtime.h>
#include <math.h>

// Problem constants (reference: B,F,W,H,D = 128,1024,32,64,64)
#define B_   128
#define F_   1024
#define W_   32
#define H_   64
#define K4H  256          // 4*H
#define K2_  (2 * F_)     // 2048: fp32 split into interleaved (hi,lo) bf16 pairs
#define KU_  (K2_ / 2)    // 1024 packed uints per B2 row

typedef __attribute__((ext_vector_type(8))) short  short8;  // 8 bf16 (MFMA A/B frag)
typedef __attribute__((ext_vector_type(4))) float  f32x4;   // MFMA C/D frag

// ---------------------------------------------------------------------------
// fp32 -> (hi,lo) bf16 pair packed into one uint: short[0]=hi (k2 even),
// short[1]=lo (k2 odd). hi=RNE(v), lo=RNE(v-hi) -> fp32 product via plain
// bf16 MFMA over doubled K, near-exact.
// ---------------------------------------------------------------------------
__device__ __forceinline__ unsigned bf16_rne(float v) {
  unsigned u = __float_as_uint(v);
  return (u + 0x7FFFu + ((u >> 16) & 1u)) >> 16;
}
__device__ __forceinline__ unsigned pack_hilo(float v) {
  unsigned hi = bf16_rne(v);
  float    hf = __uint_as_float(hi << 16);
  unsigned lo = bf16_rne(v - hf);
  return hi | (lo << 16);
}

// ---------------------------------------------------------------------------
// Wx [F,4H] fp32 -> B2 [4H][KU_] uints (transposed, hi/lo packed). Runs once
// per call; dedups the 13-VALU-op pack_hilo across the 128 fused blocks.
// ---------------------------------------------------------------------------
__global__ __launch_bounds__(256) void conv_w(const float* __restrict__ Wx,
                                              unsigned* __restrict__ B2) {
  __shared__ unsigned T[256][17];  // [n][f_local], +1 pad
  const int tid = threadIdx.x;
  const int f0  = blockIdx.x * 16;
#pragma unroll
  for (int i = 0; i < 4; ++i) {
    int l = tid + i * 256;          // 1024 float4 slots = 16 f x 64 n-groups
    int n0 = (l & 63) * 4;
    int fl = l >> 6;                // 0..15
    float4 v = *(const float4*)&Wx[(size_t)(f0 + fl) * K4H + n0];
    T[n0 + 0][fl] = pack_hilo(v.x);
    T[n0 + 1][fl] = pack_hilo(v.y);
    T[n0 + 2][fl] = pack_hilo(v.z);
    T[n0 + 3][fl] = pack_hilo(v.w);
  }
  __syncthreads();
#pragma unroll
  for (int i = 0; i < 4; ++i) {
    int l  = tid + i * 256;         // 1024 uint4 slots = 256 n x 4
    int c4 = (l & 3) * 4;
    int n  = l >> 2;
    uint4 o;
    o.x = T[n][c4 + 0]; o.y = T[n][c4 + 1]; o.z = T[n][c4 + 2]; o.w = T[n][c4 + 3];
    *(uint4*)&B2[(size_t)n * KU_ + f0 + c4] = o;
  }
}

// ---------------------------------------------------------------------------
__device__ __forceinline__ float bcastlane(float v, int l) {
  return __uint_as_float(__builtin_amdgcn_readlane(__float_as_uint(v), l));
}
__device__ __forceinline__ float sigm(float v)   { return 1.f / (1.f + __expf(-v)); }
__device__ __forceinline__ float tanh_f(float v) { return 1.f - 2.f / (__expf(2.f * v) + 1.f); }

// ---------------------------------------------------------------------------
// Fused per-batch kernel: phase 1 = gate GEMM G[32,256] = x_b @ Wx via
// hi/lo-bf16 MFMA (attention softmax over size-1 axis == identity), K=2048
// reduced fully in the accumulator chain (no K-split partials, no Gp global
// round-trip). Accumulators -> LDS (sG, 33 KB). Phase 2 = sequential LSTM
// reading sG from LDS (2-cyc latency vs ~700-cyc Gp global loads before).
// 4 waves, wave w owns gate-column strip w*64..w*64+63 in BOTH phases.
// Staging mirrors the R1-verified gemm_mfma pattern (36-uint padded rows,
// XOR-spread A writes -> 0 LDS bank conflicts measured).
// ---------------------------------------------------------------------------
__global__ __launch_bounds__(256, 1) void fused_rnn(
    const float* __restrict__ x,      // [B, F, W]
    const unsigned* __restrict__ B2,  // [4H][KU_] packed
    const float* __restrict__ Wh,     // [H, 4H]
    const float* __restrict__ bl,     // [4H]
    float* __restrict__ out) {        // [B, W, H]
  __shared__ unsigned lA[32 * 36];    // A stage: 32 t x 32 f-uints (+pad)
  __shared__ unsigned lB[256 * 36];   // B stage: 256 n x 32 f-uints (+pad)
  __shared__ float    sG[32][260];    // gate pre-activations, +4 pad
  __shared__ float    sact[2][4][64]; // [t-parity][gate-wave][u]

  const int tid  = threadIdx.x;
  const int b    = blockIdx.x;               // one block per batch element
  const int wv   = tid >> 6, lane = tid & 63;
  const int lm   = lane & 15, q = lane >> 4; // MFMA lane decomposition

  f32x4 acc[2][4];                           // 32 t x 64 n per wave
#pragma unroll
  for (int a = 0; a < 2; ++a)
#pragma unroll
    for (int bb = 0; bb < 4; ++bb) acc[a][bb] = (f32x4){0.f, 0.f, 0.f, 0.f};

  const int t0 = (tid & 7) * 4;     // A: 256 float4 = 32 f x 8 t-groups
  const int fl = tid >> 3;          // 0..31
  const int jx = (tid >> 3) & 3;    // XOR bank-spread for A's b32 writes

  float4 ax;
  uint4  bxr[8];

  auto prefetch = [&](int iter) {
    const int f0 = iter * 32;
    ax = *(const float4*)&x[((size_t)b * F_ + (f0 + fl)) * W_ + t0];
#pragma unroll
    for (int i = 0; i < 8; ++i) {   // 2048 uint4 = 256 n x 8
      int l   = tid + i * 256;
      int c16 = l & 7;
      int nl  = l >> 3;
      bxr[i] = *(const uint4*)&B2[(size_t)nl * KU_ + f0 + c16 * 4];
    }
  };

  prefetch(0);
  for (int iter = 0; iter < 32; ++iter) {    // 32 stages x 32 f = K=1024
    __syncthreads();                         // previous stage's frag reads done
    {
      float vals[4] = {ax.x, ax.y, ax.z, ax.w};
#pragma unroll
      for (int j = 0; j < 4; ++j) {          // A: convert + transpose (t -> row)
        int jj = j ^ jx;
        lA[(t0 + jj) * 36 + fl] = pack_hilo(vals[jj]);
      }
    }
#pragma unroll
    for (int i = 0; i < 8; ++i) {            // B: straight b128 copy (pre-packed)
      int l   = tid + i * 256;
      int c16 = l & 7;
      int nl  = l >> 3;
      *(uint4*)&lB[nl * 36 + c16 * 4] = bxr[i];
    }
    __syncthreads();
    if (iter + 1 < 32) prefetch(iter + 1);   // overlap globals with MFMA
#pragma unroll
    for (int step = 0; step < 2; ++step) {   // 2 x K2=32 MFMA steps
      short8 aF[2], bF[4];
#pragma unroll
      for (int mt = 0; mt < 2; ++mt)         // A[m=lane&15][k=q*8+j]
        aF[mt] = *(const short8*)&lA[(mt * 16 + lm) * 36 + step * 16 + q * 4];
#pragma unroll
      for (int nt = 0; nt < 4; ++nt)         // B[k=q*8+j][n=lane&15]
        bF[nt] = *(const short8*)&lB[(wv * 64 + nt * 16 + lm) * 36 + step * 16 + q * 4];
#pragma unroll
      for (int mt = 0; mt < 2; ++mt)
#pragma unroll
        for (int nt = 0; nt < 4; ++nt)
          acc[mt][nt] = __builtin_amdgcn_mfma_f32_16x16x32_bf16(
              aF[mt], bF[nt], acc[mt][nt], 0, 0, 0);
    }
  }

  // Phase 2 setup: issue Wh column loads NOW so their ~500-cyc latency hides
  // under the sG exchange + barrier. Thread (wv,lane) owns gate col k.
  const int k = wv * 64 + lane;
  float wc[64];                              // Wh column k, register-resident
#pragma unroll
  for (int j = 0; j < 64; ++j) wc[j] = Wh[j * K4H + k];
  const float bk = bl[k];

  // Accumulators -> LDS. C/D layout col=lane&15, row=q*4+reg [m89-verified].
  // No barrier needed before: sG doesn't alias the staging buffers.
#pragma unroll
  for (int mt = 0; mt < 2; ++mt)
#pragma unroll
    for (int nt = 0; nt < 4; ++nt)
#pragma unroll
      for (int r = 0; r < 4; ++r)
        sG[mt * 16 + q * 4 + r][wv * 64 + nt * 16 + lm] = acc[mt][nt][r];
  __syncthreads();

  // Sequential LSTM: wave 0/1/2/3 = i/f/g/o gates (tanh branch wave-uniform).
  // h replicated per wave (lane u = h[u]); dot via readlane broadcast, 4
  // split FMA chains; one barrier/step (parity-double-buffered activation
  // exchange); c,h updated redundantly in all waves. Output = CELL state.
  float h = 0.f, c = 0.f;
  for (int t = 0; t < W_; ++t) {
    float a0 = sG[t][k] + bk, a1 = 0.f, a2 = 0.f, a3 = 0.f;
#pragma unroll
    for (int j = 0; j < 64; j += 4) {        // 4 independent FMA chains
      a0 = fmaf(bcastlane(h, j),     wc[j],     a0);
      a1 = fmaf(bcastlane(h, j + 1), wc[j + 1], a1);
      a2 = fmaf(bcastlane(h, j + 2), wc[j + 2], a2);
      a3 = fmaf(bcastlane(h, j + 3), wc[j + 3], a3);
    }
    float g = (a0 + a1) + (a2 + a3);
    float act = (wv == 2) ? tanh_f(g) : sigm(g);  // wave-uniform branch
    sact[t & 1][wv][lane] = act;
    __syncthreads();                         // the single barrier per step
    float si = sact[t & 1][0][lane];
    float sf = sact[t & 1][1][lane];
    float tg = sact[t & 1][2][lane];
    float so = sact[t & 1][3][lane];
    c = fmaf(sf, c, si * tg);                // replicated in all 4 waves
    h = so * tanh_f(c);
    if (wv == 0) out[((size_t)b * W_ + t) * H_ + lane] = c;  // cell state out
  }
}

// ---------------------------------------------------------------------------
extern "C" void kernel_launch(void* const* d_in, const int* in_sizes, int n_in,
                              void* d_out, int out_size, void* d_ws, size_t ws_size,
                              hipStream_t stream) {
  // 0:x 1:W_state 2:b_state 3:W_in 4:w_attn 5:b_attn 6:Wx 7:Wh 8:b_lstm
  const float* x      = (const float*)d_in[0];
  const float* Wx     = (const float*)d_in[6];
  const float* Wh     = (const float*)d_in[7];
  const float* b_lstm = (const float*)d_in[8];
  float* out = (float*)d_out;

  // Only 1 MB of workspace needed now (packed B2); harness provides >=256 MB.
  unsigned* B2 = (unsigned*)d_ws;

  conv_w   <<<dim3(64), dim3(256), 0, stream>>>(Wx, B2);
  fused_rnn<<<dim3(B_), dim3(256), 0, stream>>>(x, B2, Wh, b_lstm, out);
}

// Round 2
// 148.943 us; speedup vs baseline: 1.2004x; 1.2004x over previous
//
#include <hip/hip_runtime.h>
#include <math.h>

// Problem constants (reference: B,F,W,H,D = 128,1024,32,64,64)
#define B_   128
#define F_   1024
#define W_   32
#define H_   64
#define K4H  256          // 4*H
#define K2_  (2 * F_)     // 2048: fp32 split into interleaved (hi,lo) bf16 pairs
#define KU_  (K2_ / 2)    // 1024 packed uints per B2 row

typedef __attribute__((ext_vector_type(8))) short  short8;  // 8 bf16 (MFMA A/B frag)
typedef __attribute__((ext_vector_type(4))) float  f32x4;   // MFMA C/D frag

// ---------------------------------------------------------------------------
// fp32 -> (hi,lo) bf16 pair packed into one uint: short[0]=hi (k2 even),
// short[1]=lo (k2 odd). hi=RNE(v), lo=RNE(v-hi) -> fp32 product via plain
// bf16 MFMA over doubled K, near-exact.
// ---------------------------------------------------------------------------
__device__ __forceinline__ unsigned bf16_rne(float v) {
  unsigned u = __float_as_uint(v);
  return (u + 0x7FFFu + ((u >> 16) & 1u)) >> 16;
}
__device__ __forceinline__ unsigned pack_hilo(float v) {
  unsigned hi = bf16_rne(v);
  float    hf = __uint_as_float(hi << 16);
  unsigned lo = bf16_rne(v - hf);
  return hi | (lo << 16);
}
__device__ __forceinline__ short8 as_s8(uint4 v) {
  union { uint4 u; short8 s; } x; x.u = v; return x.s;
}

// ---------------------------------------------------------------------------
// Wx [F,4H] fp32 -> B2 [4H][KU_] uints, transposed, hi/lo packed, and
// GRANULE-PERMUTED so a lane's MFMA B-fragments are contiguous: within each
// 32-uint K-tile, old granule (s*4+q) [s=step,q=MFMA quad] is stored at
// granule (q*2+s). Lane (n=lm,q) then reads its step-0/step-1 frags as two
// adjacent uint4 at col q*8 / q*8+4 -> 32B contiguous per lane, 128B-line
// footprint per row across the 4 q-lanes.
// ---------------------------------------------------------------------------
__global__ __launch_bounds__(256) void conv_w(const float* __restrict__ Wx,
                                              unsigned* __restrict__ B2) {
  __shared__ unsigned T[256][17];  // [n][f_local], +1 pad
  const int tid = threadIdx.x;
  const int f0  = blockIdx.x * 16;
#pragma unroll
  for (int i = 0; i < 4; ++i) {
    int l = tid + i * 256;          // 1024 float4 slots = 16 f x 64 n-groups
    int n0 = (l & 63) * 4;
    int fl = l >> 6;                // 0..15
    float4 v = *(const float4*)&Wx[(size_t)(f0 + fl) * K4H + n0];
    T[n0 + 0][fl] = pack_hilo(v.x);
    T[n0 + 1][fl] = pack_hilo(v.y);
    T[n0 + 2][fl] = pack_hilo(v.z);
    T[n0 + 3][fl] = pack_hilo(v.w);
  }
  __syncthreads();
  const int tb = f0 & ~31;          // 32-uint K-tile base
  const int s  = (f0 >> 4) & 1;    // which MFMA k-step this 16-f chunk is
#pragma unroll
  for (int i = 0; i < 4; ++i) {
    int l  = tid + i * 256;         // 1024 uint4 slots = 256 n x 4 granules
    int qg = l & 3;                 // MFMA q-group of this granule
    int n  = l >> 2;
    int c4 = qg * 4;
    uint4 o;
    o.x = T[n][c4 + 0]; o.y = T[n][c4 + 1]; o.z = T[n][c4 + 2]; o.w = T[n][c4 + 3];
    *(uint4*)&B2[(size_t)n * KU_ + tb + qg * 8 + s * 4] = o;
  }
}

// ---------------------------------------------------------------------------
__device__ __forceinline__ float bcastlane(float v, int l) {
  return __uint_as_float(__builtin_amdgcn_readlane(__float_as_uint(v), l));
}
__device__ __forceinline__ float sigm(float v)   { return 1.f / (1.f + __expf(-v)); }
__device__ __forceinline__ float tanh_f(float v) { return 1.f - 2.f / (__expf(2.f * v) + 1.f); }

// ---------------------------------------------------------------------------
// Fused per-batch kernel, restructured from R1 (105us -> target ~30us):
//  - B-fragments go GLOBAL->VGPR directly (granule-permuted B2), prefetched
//    one stage ahead into bxr. No lB staging: LDS pipe traffic per stage
//    drops 84KB -> ~13KB (A only).
//  - lA double-buffered -> ONE barrier per stage (was 2 + full drains).
//  - x prefetched two stages deep; all global loads issue at the top of the
//    body so the whole body covers their latency.
//  - #pragma unroll 1 keeps the hot loop inside L1I.
// Phase 2 (sequential LSTM over sG in LDS) unchanged except a 1-step sG
// prefetch to hide LDS read latency.
// ---------------------------------------------------------------------------
__global__ __launch_bounds__(256, 1) void fused_rnn(
    const float* __restrict__ x,      // [B, F, W]
    const unsigned* __restrict__ B2,  // [4H][KU_] packed+permuted
    const float* __restrict__ Wh,     // [H, 4H]
    const float* __restrict__ bl,     // [4H]
    float* __restrict__ out) {        // [B, W, H]
  __shared__ unsigned lA[2][32 * 36]; // A stage, double-buffered (+pad rows)
  __shared__ float    sG[32][260];    // gate pre-activations, +4 pad
  __shared__ float    sact[2][4][64]; // [t-parity][gate-wave][u]

  const int tid  = threadIdx.x;
  const int b    = blockIdx.x;               // one block per batch element
  const int wv   = tid >> 6, lane = tid & 63;
  const int lm   = lane & 15, q = lane >> 4; // MFMA lane decomposition

  f32x4 acc[2][4];                           // 32 t x 64 n per wave
#pragma unroll
  for (int a = 0; a < 2; ++a)
#pragma unroll
    for (int bb = 0; bb < 4; ++bb) acc[a][bb] = (f32x4){0.f, 0.f, 0.f, 0.f};

  const int t0 = (tid & 7) * 4;     // A: 256 float4 = 32 f x 8 t-groups
  const int fl = tid >> 3;          // 0..31
  const int jx = fl & 3;            // XOR bank-spread for A's b32 writes

  uint4 bxr[8];                     // B frags for next stage: [nt*2+step]
  auto loadB = [&](int it) {
    const int f0 = it * 32;
#pragma unroll
    for (int nt = 0; nt < 4; ++nt) {
      const unsigned* p = &B2[(size_t)(wv * 64 + nt * 16 + lm) * KU_ + f0 + q * 8];
      bxr[nt * 2 + 0] = *(const uint4*)p;        // step-0 frag
      bxr[nt * 2 + 1] = *(const uint4*)(p + 4);  // step-1 frag
    }
  };
  auto loadx = [&](int it) -> float4 {
    return *(const float4*)&x[((size_t)b * F_ + (it * 32 + fl)) * W_ + t0];
  };
  auto packA = [&](int buf, float4 v) {
    float vals[4] = {v.x, v.y, v.z, v.w};
#pragma unroll
    for (int j = 0; j < 4; ++j) {   // convert + transpose (t -> row)
      int jj = j ^ jx;
      lA[buf][(t0 + jj) * 36 + fl] = pack_hilo(vals[jj]);
    }
  };

  // Prologue: stage 0's A into buf 0, B into regs, x(1) in flight.
  float4 axc = loadx(0);
  loadB(0);
  packA(0, axc);
  float4 axn = loadx(1);
  __syncthreads();

#pragma unroll 1
  for (int iter = 0; iter < 32; ++iter) {
    // Consume this stage's B frags, immediately refill bxr for next stage.
    uint4 bF[8];
#pragma unroll
    for (int i = 0; i < 8; ++i) bF[i] = bxr[i];
    if (iter + 1 < 32) loadB(iter + 1);

    // A frags from the current buffer.
    short8 aF[2][2];
#pragma unroll
    for (int mt = 0; mt < 2; ++mt)
#pragma unroll
      for (int st = 0; st < 2; ++st)
        aF[mt][st] = *(const short8*)
            &lA[iter & 1][(mt * 16 + lm) * 36 + st * 16 + q * 4];

    // Write next stage's A into the other buffer; fetch x two stages ahead.
    if (iter + 1 < 32) {
      packA((iter + 1) & 1, axn);
      int it2 = (iter + 2 < 32) ? iter + 2 : 31;
      axn = loadx(it2);
    }

    // 16 MFMAs (2 k-steps x 2 m-tiles x 4 n-tiles).
#pragma unroll
    for (int st = 0; st < 2; ++st)
#pragma unroll
      for (int mt = 0; mt < 2; ++mt)
#pragma unroll
        for (int nt = 0; nt < 4; ++nt)
          acc[mt][nt] = __builtin_amdgcn_mfma_f32_16x16x32_bf16(
              aF[mt][st], as_s8(bF[nt * 2 + st]), acc[mt][nt], 0, 0, 0);

    __syncthreads();   // next-A writes visible; this-A reads done
  }

  // Phase 2 setup: issue Wh column loads NOW so their latency hides under
  // the sG exchange + barrier. Thread (wv,lane) owns gate col k.
  const int k = wv * 64 + lane;
  float wc[64];                              // Wh column k, register-resident
#pragma unroll
  for (int j = 0; j < 64; ++j) wc[j] = Wh[j * K4H + k];
  const float bk = bl[k];

  // Accumulators -> LDS. C/D layout col=lane&15, row=q*4+reg [m89-verified].
#pragma unroll
  for (int mt = 0; mt < 2; ++mt)
#pragma unroll
    for (int nt = 0; nt < 4; ++nt)
#pragma unroll
      for (int r = 0; r < 4; ++r)
        sG[mt * 16 + q * 4 + r][wv * 64 + nt * 16 + lm] = acc[mt][nt][r];
  __syncthreads();

  // Sequential LSTM: wave 0/1/2/3 = i/f/g/o gates (tanh branch wave-uniform).
  // h replicated per wave; dot via readlane broadcast, 4 split FMA chains;
  // one barrier/step (parity-double-buffered activation exchange).
  float h = 0.f, c = 0.f;
  float gc = sG[0][k];
#pragma unroll 1
  for (int t = 0; t < W_; ++t) {
    float gn = (t + 1 < W_) ? sG[t + 1][k] : 0.f;  // hide LDS latency
    float a0 = gc + bk, a1 = 0.f, a2 = 0.f, a3 = 0.f;
#pragma unroll
    for (int j = 0; j < 64; j += 4) {        // 4 independent FMA chains
      a0 = fmaf(bcastlane(h, j),     wc[j],     a0);
      a1 = fmaf(bcastlane(h, j + 1), wc[j + 1], a1);
      a2 = fmaf(bcastlane(h, j + 2), wc[j + 2], a2);
      a3 = fmaf(bcastlane(h, j + 3), wc[j + 3], a3);
    }
    float g = (a0 + a1) + (a2 + a3);
    float act = (wv == 2) ? tanh_f(g) : sigm(g);  // wave-uniform branch
    sact[t & 1][wv][lane] = act;
    __syncthreads();                         // the single barrier per step
    float si = sact[t & 1][0][lane];
    float sf = sact[t & 1][1][lane];
    float tg = sact[t & 1][2][lane];
    float so = sact[t & 1][3][lane];
    c = fmaf(sf, c, si * tg);                // replicated in all 4 waves
    h = so * tanh_f(c);
    if (wv == 0) out[((size_t)b * W_ + t) * H_ + lane] = c;  // cell state out
    gc = gn;
  }
}

// ---------------------------------------------------------------------------
extern "C" void kernel_launch(void* const* d_in, const int* in_sizes, int n_in,
                              void* d_out, int out_size, void* d_ws, size_t ws_size,
                              hipStream_t stream) {
  // 0:x 1:W_state 2:b_state 3:W_in 4:w_attn 5:b_attn 6:Wx 7:Wh 8:b_lstm
  const float* x      = (const float*)d_in[0];
  const float* Wx     = (const float*)d_in[6];
  const float* Wh     = (const float*)d_in[7];
  const float* b_lstm = (const float*)d_in[8];
  float* out = (float*)d_out;

  // Only 1 MB of workspace needed (packed+permuted B2).
  unsigned* B2 = (unsigned*)d_ws;

  conv_w   <<<dim3(64), dim3(256), 0, stream>>>(Wx, B2);
  fused_rnn<<<dim3(B_), dim3(256), 0, stream>>>(x, B2, Wh, b_lstm, out);
}